// Round 1
// baseline (181.144 us; speedup 1.0000x reference)
//
#include <hip/hip_runtime.h>
#include <stdint.h>

#define BATCH 4096
#define N_IN  512
#define H1    1536
#define H2    1536
#define N_OUT 512
#define FAN   32
#define E0 (H1 * FAN)
#define E1 (H2 * FAN)
#define E2 (N_OUT * FAN)
#define ETOT (E0 + E1 + E2)

// ---- workspace layout (bytes) ----
// nvT   (bf16, rows = global node id 0..4095? we use 0..3583): 3584*4096*2 = 29,360,128
// outT  (fp32, 512 x 4096)                                   :  8,388,608
// edges (int2: src, w-bits), CSR-sorted, 3 levels packed     :    917,504
// row_ptr (1537 + 1537 + 513 ints)                           :     14,592 (padded)
// cursor  (3584 ints)                                        :     14,336
// counts  (3584 ints)                                        :     14,336
#define OFF_OUTT   29360128
#define OFF_EDGES  37748736
#define OFF_RP     38666240
#define OFF_CUR    38680832
#define OFF_CNT    38695168

__device__ __forceinline__ uint32_t f2bf(float f) {
    uint32_t u = __float_as_uint(f);
    return (u + 0x7fffu + ((u >> 16) & 1u)) >> 16;   // RNE bf16
}

// ---------- x [B, N_IN] fp32 -> xT [N_IN, B] bf16 (rows 0..511 of nvT) ----------
__global__ __launch_bounds__(256) void k_transpose_in(const float* __restrict__ x,
                                                      uint16_t* __restrict__ xT) {
    __shared__ float tile[32][33];
    const int tx = threadIdx.x, ty = threadIdx.y;   // 32 x 8
    const int n0 = blockIdx.x * 32;                 // node base
    const int b0 = blockIdx.y * 32;                 // batch base
#pragma unroll
    for (int k = 0; k < 32; k += 8)
        tile[ty + k][tx] = x[(size_t)(b0 + ty + k) * N_IN + (n0 + tx)];
    __syncthreads();
#pragma unroll
    for (int k = 0; k < 32; k += 8)
        xT[(size_t)(n0 + ty + k) * BATCH + (b0 + tx)] = (uint16_t)f2bf(tile[tx][ty + k]);
}

// ---------- CSR build ----------
__global__ __launch_bounds__(256) void k_zero(int* __restrict__ p) {
    p[blockIdx.x * 256 + threadIdx.x] = 0;
}

__global__ __launch_bounds__(256) void k_count(const int* __restrict__ d0,
                                               const int* __restrict__ d1,
                                               const int* __restrict__ d2,
                                               int* __restrict__ counts) {
    const int e = blockIdx.x * 256 + threadIdx.x;
    if (e < E0)            atomicAdd(&counts[d0[e]], 1);
    else if (e < E0 + E1)  atomicAdd(&counts[H1 + d1[e - E0]], 1);
    else                   atomicAdd(&counts[H1 + H2 + d2[e - E0 - E1]], 1);
}

// one block per level: exclusive scan of counts -> row_ptr (level-local), cursor copy
__global__ __launch_bounds__(256) void k_scan(const int* __restrict__ counts,
                                              int* __restrict__ row_ptr,
                                              int* __restrict__ cursor) {
    const int lvl   = blockIdx.x;
    const int n     = (lvl == 2) ? N_OUT : H1;
    const int cbase = (lvl == 0) ? 0 : (lvl == 1) ? H1 : (H1 + H2);
    const int rbase = (lvl == 0) ? 0 : (lvl == 1) ? (H1 + 1) : (H1 + 1 + H2 + 1);
    const int t = threadIdx.x;
    const int chunk = n / 256;                      // 6, 6, 2 — exact
    int local[8];
    int sum = 0;
    for (int j = 0; j < chunk; ++j) {
        local[j] = counts[cbase + t * chunk + j];
        sum += local[j];
    }
    __shared__ int s[256];
    s[t] = sum;
    __syncthreads();
    for (int off = 1; off < 256; off <<= 1) {
        int v = (t >= off) ? s[t - off] : 0;
        __syncthreads();
        s[t] += v;
        __syncthreads();
    }
    int base = (t == 0) ? 0 : s[t - 1];
    for (int j = 0; j < chunk; ++j) {
        row_ptr[rbase + t * chunk + j] = base;
        cursor[cbase + t * chunk + j]  = base;
        base += local[j];
    }
    if (t == 255) row_ptr[rbase + n] = base;
}

__global__ __launch_bounds__(256) void k_fill(const int* __restrict__ s0, const int* __restrict__ d0, const float* __restrict__ w0,
                                              const int* __restrict__ s1, const int* __restrict__ d1, const float* __restrict__ w1,
                                              const int* __restrict__ s2, const int* __restrict__ d2, const float* __restrict__ w2,
                                              int* __restrict__ cursor, int2* __restrict__ edges) {
    const int e = blockIdx.x * 256 + threadIdx.x;
    int src, node, ebase; float w;
    if (e < E0)           { src = s0[e];            node = d0[e];                 w = w0[e];            ebase = 0; }
    else if (e < E0 + E1) { int i = e - E0;         src = s1[i]; node = H1 + d1[i];        w = w1[i];   ebase = E0; }
    else                  { int i = e - E0 - E1;    src = s2[i]; node = H1 + H2 + d2[i];   w = w2[i];   ebase = E0 + E1; }
    const int pos = atomicAdd(&cursor[node], 1);
    edges[ebase + pos] = make_int2(src, __float_as_int(w));
}

// ---------- level kernel: per-node CSR reduction over a 512-column batch tile ----------
// grid (8 tiles, H nodes), block 128; thread = 4 bf16 columns (one 8B load/edge)
template <bool FP32OUT>
__global__ __launch_bounds__(128)
void k_level(const int2* __restrict__ edges,
             const int* __restrict__ row_ptr,
             const uint32_t* __restrict__ nv,     // nvT viewed as u32 pairs
             uint32_t* __restrict__ outb,         // bf16 out rows (pre-offset), levels 0/1
             float* __restrict__ outf) {          // fp32 out, level 2
    const int node = blockIdx.y;
    const int col  = (blockIdx.x << 9) | (threadIdx.x << 2);
    int e = row_ptr[node];
    const int end = row_ptr[node + 1];
    float a0 = 0.f, a1 = 0.f, a2 = 0.f, a3 = 0.f;
    for (; e + 2 <= end; e += 2) {
        const int2 ed0 = edges[e];
        const int2 ed1 = edges[e + 1];
        const uint2 v0 = *(const uint2*)(nv + ((((size_t)ed0.x << 12) | col) >> 1));
        const uint2 v1 = *(const uint2*)(nv + ((((size_t)ed1.x << 12) | col) >> 1));
        const float w0 = __int_as_float(ed0.y);
        const float w1 = __int_as_float(ed1.y);
        a0 = fmaf(__uint_as_float(v0.x << 16), w0, a0);
        a1 = fmaf(__uint_as_float(v0.x & 0xffff0000u), w0, a1);
        a2 = fmaf(__uint_as_float(v0.y << 16), w0, a2);
        a3 = fmaf(__uint_as_float(v0.y & 0xffff0000u), w0, a3);
        a0 = fmaf(__uint_as_float(v1.x << 16), w1, a0);
        a1 = fmaf(__uint_as_float(v1.x & 0xffff0000u), w1, a1);
        a2 = fmaf(__uint_as_float(v1.y << 16), w1, a2);
        a3 = fmaf(__uint_as_float(v1.y & 0xffff0000u), w1, a3);
    }
    if (e < end) {
        const int2 ed0 = edges[e];
        const uint2 v0 = *(const uint2*)(nv + ((((size_t)ed0.x << 12) | col) >> 1));
        const float w0 = __int_as_float(ed0.y);
        a0 = fmaf(__uint_as_float(v0.x << 16), w0, a0);
        a1 = fmaf(__uint_as_float(v0.x & 0xffff0000u), w0, a1);
        a2 = fmaf(__uint_as_float(v0.y << 16), w0, a2);
        a3 = fmaf(__uint_as_float(v0.y & 0xffff0000u), w0, a3);
    }
    a0 = fmaxf(a0, 0.f); a1 = fmaxf(a1, 0.f); a2 = fmaxf(a2, 0.f); a3 = fmaxf(a3, 0.f);
    if (FP32OUT) {
        float4 r; r.x = a0; r.y = a1; r.z = a2; r.w = a3;
        *(float4*)(outf + (((size_t)node << 12) | col)) = r;
    } else {
        uint2 p;
        p.x = f2bf(a0) | (f2bf(a1) << 16);
        p.y = f2bf(a2) | (f2bf(a3) << 16);
        *(uint2*)(outb + ((((size_t)node << 12) | col) >> 1)) = p;
    }
}

// ---------- outT [N_OUT, B] fp32 -> out [B, N_OUT] fp32 ----------
__global__ __launch_bounds__(256) void k_transpose_out(const float* __restrict__ outT,
                                                       float* __restrict__ out) {
    __shared__ float tile[32][33];
    const int tx = threadIdx.x, ty = threadIdx.y;   // 32 x 8
    const int n0 = blockIdx.x * 32;
    const int b0 = blockIdx.y * 32;
#pragma unroll
    for (int k = 0; k < 32; k += 8)
        tile[ty + k][tx] = outT[(size_t)(n0 + ty + k) * BATCH + (b0 + tx)];
    __syncthreads();
#pragma unroll
    for (int k = 0; k < 32; k += 8)
        out[(size_t)(b0 + ty + k) * N_OUT + (n0 + tx)] = tile[tx][ty + k];
}

extern "C" void kernel_launch(void* const* d_in, const int* in_sizes, int n_in,
                              void* d_out, int out_size, void* d_ws, size_t ws_size,
                              hipStream_t stream) {
    const float* x  = (const float*)d_in[0];
    const int* s0   = (const int*)d_in[1];
    const int* dd0  = (const int*)d_in[2];
    const float* w0 = (const float*)d_in[3];
    const int* s1   = (const int*)d_in[4];
    const int* dd1  = (const int*)d_in[5];
    const float* w1 = (const float*)d_in[6];
    const int* s2   = (const int*)d_in[7];
    const int* dd2  = (const int*)d_in[8];
    const float* w2 = (const float*)d_in[9];

    char* ws        = (char*)d_ws;
    uint32_t* nv    = (uint32_t*)ws;                 // nvT bf16 as u32 pairs
    float*    outT  = (float*)(ws + OFF_OUTT);
    int2*     edges = (int2*)(ws + OFF_EDGES);
    int*      rp    = (int*)(ws + OFF_RP);           // [0..1536], [1537..3073], [3074..3586]
    int*      cur   = (int*)(ws + OFF_CUR);
    int*      cnt   = (int*)(ws + OFF_CNT);

    // CSR build
    k_zero<<<14, 256, 0, stream>>>(cnt);
    k_count<<<ETOT / 256, 256, 0, stream>>>(dd0, dd1, dd2, cnt);
    k_scan<<<3, 256, 0, stream>>>(cnt, rp, cur);
    k_fill<<<ETOT / 256, 256, 0, stream>>>(s0, dd0, w0, s1, dd1, w1, s2, dd2, w2, cur, edges);

    // x -> bf16 transposed node-value rows 0..511
    k_transpose_in<<<dim3(N_IN / 32, BATCH / 32), dim3(32, 8), 0, stream>>>(x, (uint16_t*)nv);

    // levels
    k_level<false><<<dim3(8, H1), 128, 0, stream>>>(edges, rp, nv,
                                                    nv + ((size_t)N_IN * BATCH / 2), nullptr);
    k_level<false><<<dim3(8, H2), 128, 0, stream>>>(edges + E0, rp + (H1 + 1), nv,
                                                    nv + ((size_t)(N_IN + H1) * BATCH / 2), nullptr);
    k_level<true><<<dim3(8, N_OUT), 128, 0, stream>>>(edges + E0 + E1, rp + (H1 + 1 + H2 + 1), nv,
                                                      nullptr, outT);

    // outT -> d_out [B, N_OUT]
    k_transpose_out<<<dim3(N_OUT / 32, BATCH / 32), dim3(32, 8), 0, stream>>>(outT, (float*)d_out);
}